// Round 4
// baseline (113.670 us; speedup 1.0000x reference)
//
#include <hip/hip_runtime.h>
#include <math.h>

// YOLO loss on MI355X. prediction (N,7,7,30) f32, target (N,7,7,25) f32.
// Persistent 1-wave blocks, 4 tiles of 64 cells each, register-prefetch
// software pipeline: global->VGPR loads for tile k+1 issued before computing
// tile k from LDS; committed to LDS after compute (same-wave DS ops are
// in-order, so single LDS buffer is safe). Reduction amortized to once/block.
constexpr int TOT   = 16384 * 7 * 7;      // 802816 cells
constexpr int TILE  = 64;                 // cells per tile
constexpr int NT    = 4;                  // tiles per block
constexpr int NBLK  = TOT / (TILE * NT);  // 3136, exact
constexpr int NSLOT = 64;                 // spread accumulator slots
constexpr int SLOT_STRIDE = 32;           // floats (128 B) per slot
constexpr float INV_N = 1.0f / 16384.0f;
constexpr float INV7  = 1.0f / 7.0f;      // replaces /7.0f (threshold 2.84 abs)

__device__ __forceinline__ float fast_rcp(float x) {
    return __builtin_amdgcn_rcpf(x);      // v_rcp_f32, ~1ulp
}

__global__ __launch_bounds__(64, 3) void yolo_partial(
    const float* __restrict__ pred, const float* __restrict__ tgt,
    float* __restrict__ acc /* NSLOT*SLOT_STRIDE f32, pre-zeroed */)
{
    // 64*30 + 64*25 floats = 880 float4 = 14080 B (single buffer)
    __shared__ float4 smem4[880];
    float* pred_s = (float*)smem4;          // stride 30 floats
    float* tgt_s  = pred_s + TILE * 30;     // stride 25 floats

    const int l  = threadIdx.x;             // 0..63, one wave
    const int tb = blockIdx.x * NT;

    float a_xy = 0.0f, a_wh = 0.0f, a_co = 0.0f, a_cn = 0.0f, a_cl = 0.0f;

    // prefetch registers: pred tile = 480 float4 (7*64 + 32), tgt = 400 (6*64 + 16)
    float4 pf[15];

#define ISSUE(tile_)                                                        \
    {                                                                       \
        const float4* gp = reinterpret_cast<const float4*>(pred + (long)(tile_) * (TILE * 30)); \
        const float4* gt = reinterpret_cast<const float4*>(tgt  + (long)(tile_) * (TILE * 25)); \
        _Pragma("unroll")                                                   \
        for (int i = 0; i < 7; ++i) pf[i] = gp[l + i * 64];                 \
        if (l < 32) pf[7] = gp[l + 448];                                    \
        _Pragma("unroll")                                                   \
        for (int i = 0; i < 6; ++i) pf[8 + i] = gt[l + i * 64];             \
        if (l < 16) pf[14] = gt[l + 384];                                   \
    }

#define COMMIT()                                                            \
    {                                                                       \
        float4* sp = smem4;                                                 \
        float4* st = smem4 + 480;                                           \
        _Pragma("unroll")                                                   \
        for (int i = 0; i < 7; ++i) sp[l + i * 64] = pf[i];                 \
        if (l < 32) sp[l + 448] = pf[7];                                    \
        _Pragma("unroll")                                                   \
        for (int i = 0; i < 6; ++i) st[l + i * 64] = pf[8 + i];             \
        if (l < 16) st[l + 384] = pf[14];                                   \
    }

    ISSUE(tb);
    COMMIT();
    __syncthreads();   // one wave: cheap waitcnt+barrier

#pragma unroll
    for (int k = 0; k < NT; ++k) {
        if (k + 1 < NT) ISSUE(tb + k + 1);   // next tile's loads in flight

        // ---- compute tile k from LDS ----
        const int   cell = (tb + k) * TILE + l;
        const int   col  = cell % 7;
        const int   row  = (cell / 7) % 7;
        const float fcol = (float)col, frow = (float)row;

        float pv[30];
        {
            const float2* p2 = reinterpret_cast<const float2*>(pred_s + l * 30); // 8B-aligned
#pragma unroll
            for (int i = 0; i < 15; ++i) {
                float2 v = p2[i];
                pv[2 * i] = v.x; pv[2 * i + 1] = v.y;
            }
        }
        float tv[25];
        {
            const float* tp = tgt_s + l * 25;
#pragma unroll
            for (int kk = 0; kk < 25; ++kk) tv[kk] = tp[kk];
        }

        const float conf  = tv[4];
        const bool  noobj = (conf == 0.0f);

        // target abs corners, scaled by conf (reference: _rel2abs(target)*conf)
        float xc = (tv[0] + fcol) * INV7, yc = (tv[1] + frow) * INV7;
        float hw = tv[2] * 0.5f,          hh = tv[3] * 0.5f;
        float tx1 = (xc - hw) * conf, ty1 = (yc - hh) * conf;
        float tx2 = (xc + hw) * conf, ty2 = (yc + hh) * conf;
        float t_area = (tx2 - tx1) * (ty2 - ty1);

        // pred box 1
        float xc1 = (pv[0] + fcol) * INV7, yc1 = (pv[1] + frow) * INV7;
        float hw1 = pv[2] * 0.5f,          hh1 = pv[3] * 0.5f;
        float bx1 = xc1 - hw1, by1 = yc1 - hh1, bx2 = xc1 + hw1, by2 = yc1 + hh1;
        float xi1 = fmaxf(tx1, bx1), yi1 = fmaxf(ty1, by1);
        float xi2 = fminf(tx2, bx2), yi2 = fminf(ty2, by2);
        float inter1 = fmaxf(xi2 - xi1, 0.0f) * fmaxf(yi2 - yi1, 0.0f);
        float area1  = (bx2 - bx1) * (by2 - by1);
        float iou1 = inter1 * fast_rcp(t_area + area1 - inter1 + 1e-6f);

        // pred box 2
        float xc2 = (pv[5] + fcol) * INV7, yc2 = (pv[6] + frow) * INV7;
        float hw2 = pv[7] * 0.5f,          hh2 = pv[8] * 0.5f;
        float cx1 = xc2 - hw2, cy1 = yc2 - hh2, cx2 = xc2 + hw2, cy2 = yc2 + hh2;
        float xj1 = fmaxf(tx1, cx1), yj1 = fmaxf(ty1, cy1);
        float xj2 = fminf(tx2, cx2), yj2 = fminf(ty2, cy2);
        float inter2 = fmaxf(xj2 - xj1, 0.0f) * fmaxf(yj2 - yj1, 0.0f);
        float area2  = (cx2 - cx1) * (cy2 - cy1);
        float iou2 = inter2 * fast_rcp(t_area + area2 - inter2 + 1e-6f);

        // NB: reference as written picks box2 when iou1 > iou2
        const bool pick2 = iou1 > iou2;
        float hx  = pick2 ? pv[5] : pv[0];
        float hy  = pick2 ? pv[6] : pv[1];
        float hwv = pick2 ? pv[7] : pv[2];
        float hhv = pick2 ? pv[8] : pv[3];
        float hc  = pick2 ? pv[9] : pv[4];

        // loss_xy
        float px = noobj ? 0.0f : fmaxf(hx, 0.0f);
        float py = noobj ? 0.0f : fmaxf(hy, 0.0f);
        float dx = tv[0] - px, dy = tv[1] - py;
        a_xy += dx * dx + dy * dy;
        // loss_wh (sum of squares; sqrt in finalize)
        float pw = noobj ? 0.0f : fmaxf(hwv, 0.0f);
        float ph = noobj ? 0.0f : fmaxf(hhv, 0.0f);
        float dw = tv[2] - pw, dh = tv[3] - ph;
        a_wh += dw * dw + dh * dh;
        // conf losses
        float cc = fminf(fmaxf(hc, 0.0f), 1.0f);
        float co = noobj ? 0.0f : cc;
        float cn = noobj ? cc : 0.0f;
        float dco = conf - co, dcn = conf - cn;
        a_co += dco * dco;
        a_cn += dcn * dcn;
        // class loss
        float cl = 0.0f;
#pragma unroll
        for (int kk = 0; kk < 20; ++kk) {
            float pc = noobj ? 0.0f : pv[10 + kk];
            float d  = tv[5 + kk] - pc;
            cl += d * d;
        }
        a_cl += cl;
        // ---- end compute ----

        if (k + 1 < NT) {
            __syncthreads();   // reads of tile k done before overwrite (cheap, 1 wave)
            COMMIT();
            __syncthreads();
        }
    }

    // one wave64 butterfly reduce per block
#pragma unroll
    for (int off = 32; off > 0; off >>= 1) {
        a_xy += __shfl_down(a_xy, off);
        a_wh += __shfl_down(a_wh, off);
        a_co += __shfl_down(a_co, off);
        a_cn += __shfl_down(a_cn, off);
        a_cl += __shfl_down(a_cl, off);
    }
    if (l == 0) {
        float* slot = acc + (blockIdx.x & (NSLOT - 1)) * SLOT_STRIDE;
        atomicAdd(&slot[0], a_xy);
        atomicAdd(&slot[1], a_wh);
        atomicAdd(&slot[2], a_co);
        atomicAdd(&slot[3], a_cn);
        atomicAdd(&slot[4], a_cl);
    }
#undef ISSUE
#undef COMMIT
}

__global__ __launch_bounds__(64) void yolo_final(
    const float* __restrict__ acc, float* __restrict__ out)
{
    const int l = threadIdx.x;  // 0..63, one slot each
    float s0 = acc[l * SLOT_STRIDE + 0];
    float s1 = acc[l * SLOT_STRIDE + 1];
    float s2 = acc[l * SLOT_STRIDE + 2];
    float s3 = acc[l * SLOT_STRIDE + 3];
    float s4 = acc[l * SLOT_STRIDE + 4];
#pragma unroll
    for (int off = 32; off > 0; off >>= 1) {
        s0 += __shfl_down(s0, off);
        s1 += __shfl_down(s1, off);
        s2 += __shfl_down(s2, off);
        s3 += __shfl_down(s3, off);
        s4 += __shfl_down(s4, off);
    }
    if (l == 0) {
        float lxy = s0 * INV_N;
        float lwh = sqrtf(s1 + 1e-6f) * INV_N;
        float lco = s2 * INV_N;
        float lcn = s3 * INV_N;
        float lcl = s4 * INV_N;
        out[0] = lxy;
        out[1] = lwh;
        out[2] = lco;
        out[3] = lcn;
        out[4] = lcl;
        out[5] = 5.0f * lxy + 5.0f * lwh + lco + 0.5f * lcn + lcl;
    }
}

extern "C" void kernel_launch(void* const* d_in, const int* in_sizes, int n_in,
                              void* d_out, int out_size, void* d_ws, size_t ws_size,
                              hipStream_t stream)
{
    const float* pred = (const float*)d_in[0];
    const float* tgt  = (const float*)d_in[1];
    float* out = (float*)d_out;
    float* acc = (float*)d_ws;

    hipMemsetAsync(acc, 0, NSLOT * SLOT_STRIDE * sizeof(float), stream);
    yolo_partial<<<NBLK, 64, 0, stream>>>(pred, tgt, acc);
    yolo_final<<<1, 64, 0, stream>>>(acc, out);
}

// Round 5
// 38.183 us; speedup vs baseline: 2.9770x; 2.9770x over previous
//
#include <hip/hip_runtime.h>
#include <math.h>

// YOLO loss on MI355X. prediction (N,7,7,30) f32, target (N,7,7,25) f32.
// Double-buffered LDS pipeline via global_load_lds DMA (zero VGPR staging):
// 1-wave blocks, 5 resident/CU, each grid-strides 9-10 tiles of 64 cells.
// Per iter: issue 15 DMA for tile k+1 -> buf^1, s_waitcnt vmcnt(15) (counted,
// never 0 mid-loop), sched_barrier, compute tile k from buf. Reduce once/block.
constexpr int TOT    = 16384 * 7 * 7;        // 802816 cells
constexpr int TILE   = 64;                   // cells per tile
constexpr int NTILES = TOT / TILE;           // 12544
constexpr int NBLK   = 1280;                 // 5 blocks/CU x 256 CU, all resident
constexpr int NSLOT  = 64;                   // spread accumulator slots
constexpr int SLOT_STRIDE = 32;              // floats (128 B) per slot
constexpr float INV_N = 1.0f / 16384.0f;
constexpr float INV7  = 1.0f / 7.0f;

constexpr int PRED_TILE_B = TILE * 30 * 4;   // 7680 B  (480 float4)
constexpr int TGT_TILE_B  = TILE * 25 * 4;   // 6400 B  (400 float4)
constexpr int BUF_B       = 14336;           // per-tile LDS buffer (padded, 16-al)

__device__ __forceinline__ float fast_rcp(float x) {
    return __builtin_amdgcn_rcpf(x);         // v_rcp_f32, ~1ulp
}

// DMA 16 B per active lane: global (per-lane addr) -> LDS (wave base + lane*16)
__device__ __forceinline__ void dma16(const void* g, void* lds) {
    __builtin_amdgcn_global_load_lds(
        (const __attribute__((address_space(1))) void*)g,
        (__attribute__((address_space(3))) void*)lds, 16, 0, 0);
}

__global__ __launch_bounds__(64) void yolo_partial(
    const float* __restrict__ pred, const float* __restrict__ tgt,
    float* __restrict__ acc /* NSLOT*SLOT_STRIDE f32, pre-zeroed */)
{
    __shared__ float4 smem4[2 * BUF_B / 16];     // 28672 B, 16-B aligned
    char* smem = (char*)smem4;

    const int l   = threadIdx.x;                 // 0..63, one wave
    const int bid = blockIdx.x;

    float a_xy = 0.0f, a_wh = 0.0f, a_co = 0.0f, a_cn = 0.0f, a_cl = 0.0f;

    const int nt = (NTILES - bid + NBLK - 1) / NBLK;   // 9 or 10 tiles

    auto stage = [&](int tile, int b) {
        const char* gp = (const char*)pred + (long)tile * PRED_TILE_B;
        const char* gt = (const char*)tgt  + (long)tile * TGT_TILE_B;
        char* lb = smem + b * BUF_B;
        // pred: 7 full-wave calls (1024 B each) + half-wave tail = 7680 B
#pragma unroll
        for (int i = 0; i < 7; ++i)
            dma16(gp + (size_t)(l + i * 64) * 16, lb + i * 1024);
        if (l < 32) dma16(gp + (size_t)(l + 448) * 16, lb + 7168);
        // tgt: 6 full-wave calls + quarter-wave tail = 6400 B at LDS off 7680
#pragma unroll
        for (int i = 0; i < 6; ++i)
            dma16(gt + (size_t)(l + i * 64) * 16, lb + 7680 + i * 1024);
        if (l < 16) dma16(gt + (size_t)(l + 384) * 16, lb + 13824);
    };  // 15 vmcnt ops per tile

    stage(bid, 0);
    int buf = 0;

    for (int k = 0; k < nt; ++k) {
        const int tile = bid + k * NBLK;
        if (k + 1 < nt) {
            stage(bid + (k + 1) * NBLK, buf ^ 1);
            asm volatile("s_waitcnt vmcnt(15)" ::: "memory");  // tile k landed
        } else {
            asm volatile("s_waitcnt vmcnt(0)" ::: "memory");
        }
        __builtin_amdgcn_sched_barrier(0);   // keep ds_reads after the wait

        // ---- compute tile k from LDS buf ----
        const float* pred_s = (const float*)(smem + buf * BUF_B);
        const float* tgt_s  = pred_s + TILE * 30;

        const int   cell = tile * TILE + l;
        const int   col  = cell % 7;
        const int   row  = (cell / 7) % 7;
        const float fcol = (float)col, frow = (float)row;

        float pv[30];
        {
            const float2* p2 = reinterpret_cast<const float2*>(pred_s + l * 30); // 8B-al
#pragma unroll
            for (int i = 0; i < 15; ++i) {
                float2 v = p2[i];
                pv[2 * i] = v.x; pv[2 * i + 1] = v.y;
            }
        }
        float tv[25];
        {
            const float* tp = tgt_s + l * 25;   // stride 25: conflict-free b32
#pragma unroll
            for (int kk = 0; kk < 25; ++kk) tv[kk] = tp[kk];
        }

        const float conf  = tv[4];
        const bool  noobj = (conf == 0.0f);

        // target abs corners, scaled by conf (reference: _rel2abs(target)*conf)
        float xc = (tv[0] + fcol) * INV7, yc = (tv[1] + frow) * INV7;
        float hw = tv[2] * 0.5f,          hh = tv[3] * 0.5f;
        float tx1 = (xc - hw) * conf, ty1 = (yc - hh) * conf;
        float tx2 = (xc + hw) * conf, ty2 = (yc + hh) * conf;
        float t_area = (tx2 - tx1) * (ty2 - ty1);

        // pred box 1
        float xc1 = (pv[0] + fcol) * INV7, yc1 = (pv[1] + frow) * INV7;
        float hw1 = pv[2] * 0.5f,          hh1 = pv[3] * 0.5f;
        float bx1 = xc1 - hw1, by1 = yc1 - hh1, bx2 = xc1 + hw1, by2 = yc1 + hh1;
        float xi1 = fmaxf(tx1, bx1), yi1 = fmaxf(ty1, by1);
        float xi2 = fminf(tx2, bx2), yi2 = fminf(ty2, by2);
        float inter1 = fmaxf(xi2 - xi1, 0.0f) * fmaxf(yi2 - yi1, 0.0f);
        float area1  = (bx2 - bx1) * (by2 - by1);
        float iou1 = inter1 * fast_rcp(t_area + area1 - inter1 + 1e-6f);

        // pred box 2
        float xc2 = (pv[5] + fcol) * INV7, yc2 = (pv[6] + frow) * INV7;
        float hw2 = pv[7] * 0.5f,          hh2 = pv[8] * 0.5f;
        float cx1 = xc2 - hw2, cy1 = yc2 - hh2, cx2 = xc2 + hw2, cy2 = yc2 + hh2;
        float xj1 = fmaxf(tx1, cx1), yj1 = fmaxf(ty1, cy1);
        float xj2 = fminf(tx2, cx2), yj2 = fminf(ty2, cy2);
        float inter2 = fmaxf(xj2 - xj1, 0.0f) * fmaxf(yj2 - yj1, 0.0f);
        float area2  = (cx2 - cx1) * (cy2 - cy1);
        float iou2 = inter2 * fast_rcp(t_area + area2 - inter2 + 1e-6f);

        // NB: reference as written picks box2 when iou1 > iou2
        const bool pick2 = iou1 > iou2;
        float hx  = pick2 ? pv[5] : pv[0];
        float hy  = pick2 ? pv[6] : pv[1];
        float hwv = pick2 ? pv[7] : pv[2];
        float hhv = pick2 ? pv[8] : pv[3];
        float hc  = pick2 ? pv[9] : pv[4];

        // loss_xy
        float px = noobj ? 0.0f : fmaxf(hx, 0.0f);
        float py = noobj ? 0.0f : fmaxf(hy, 0.0f);
        float dx = tv[0] - px, dy = tv[1] - py;
        a_xy += dx * dx + dy * dy;
        // loss_wh (sum of squares; sqrt in finalize)
        float pw = noobj ? 0.0f : fmaxf(hwv, 0.0f);
        float ph = noobj ? 0.0f : fmaxf(hhv, 0.0f);
        float dw = tv[2] - pw, dh = tv[3] - ph;
        a_wh += dw * dw + dh * dh;
        // conf losses
        float cc = fminf(fmaxf(hc, 0.0f), 1.0f);
        float co = noobj ? 0.0f : cc;
        float cn = noobj ? cc : 0.0f;
        float dco = conf - co, dcn = conf - cn;
        a_co += dco * dco;
        a_cn += dcn * dcn;
        // class loss
        float cl = 0.0f;
#pragma unroll
        for (int kk = 0; kk < 20; ++kk) {
            float pc = noobj ? 0.0f : pv[10 + kk];
            float d  = tv[5 + kk] - pc;
            cl += d * d;
        }
        a_cl += cl;
        // ---- end compute ----

        buf ^= 1;
    }

    // one wave64 butterfly reduce per block
#pragma unroll
    for (int off = 32; off > 0; off >>= 1) {
        a_xy += __shfl_down(a_xy, off);
        a_wh += __shfl_down(a_wh, off);
        a_co += __shfl_down(a_co, off);
        a_cn += __shfl_down(a_cn, off);
        a_cl += __shfl_down(a_cl, off);
    }
    if (l == 0) {
        float* slot = acc + (bid & (NSLOT - 1)) * SLOT_STRIDE;
        atomicAdd(&slot[0], a_xy);
        atomicAdd(&slot[1], a_wh);
        atomicAdd(&slot[2], a_co);
        atomicAdd(&slot[3], a_cn);
        atomicAdd(&slot[4], a_cl);
    }
}

__global__ __launch_bounds__(64) void yolo_final(
    const float* __restrict__ acc, float* __restrict__ out)
{
    const int l = threadIdx.x;  // 0..63, one slot each
    float s0 = acc[l * SLOT_STRIDE + 0];
    float s1 = acc[l * SLOT_STRIDE + 1];
    float s2 = acc[l * SLOT_STRIDE + 2];
    float s3 = acc[l * SLOT_STRIDE + 3];
    float s4 = acc[l * SLOT_STRIDE + 4];
#pragma unroll
    for (int off = 32; off > 0; off >>= 1) {
        s0 += __shfl_down(s0, off);
        s1 += __shfl_down(s1, off);
        s2 += __shfl_down(s2, off);
        s3 += __shfl_down(s3, off);
        s4 += __shfl_down(s4, off);
    }
    if (l == 0) {
        float lxy = s0 * INV_N;
        float lwh = sqrtf(s1 + 1e-6f) * INV_N;
        float lco = s2 * INV_N;
        float lcn = s3 * INV_N;
        float lcl = s4 * INV_N;
        out[0] = lxy;
        out[1] = lwh;
        out[2] = lco;
        out[3] = lcn;
        out[4] = lcl;
        out[5] = 5.0f * lxy + 5.0f * lwh + lco + 0.5f * lcn + lcl;
    }
}

extern "C" void kernel_launch(void* const* d_in, const int* in_sizes, int n_in,
                              void* d_out, int out_size, void* d_ws, size_t ws_size,
                              hipStream_t stream)
{
    const float* pred = (const float*)d_in[0];
    const float* tgt  = (const float*)d_in[1];
    float* out = (float*)d_out;
    float* acc = (float*)d_ws;

    hipMemsetAsync(acc, 0, NSLOT * SLOT_STRIDE * sizeof(float), stream);
    yolo_partial<<<NBLK, 64, 0, stream>>>(pred, tgt, acc);
    yolo_final<<<1, 64, 0, stream>>>(acc, out);
}